// Round 1
// baseline (1009.306 us; speedup 1.0000x reference)
//
#include <hip/hip_runtime.h>

// AttentionLayer: B=8 T=256 M=64 D=512 H=8 DK=64.
// Plan: pack weights to bf16; fused per-(b,t) QKV+attention kernel (MFMA);
// tiled MFMA output-projection GEMM. Workspace: 136,314,880 bytes.

typedef unsigned short u16;
typedef short s4v __attribute__((ext_vector_type(4)));
typedef short s8v __attribute__((ext_vector_type(8)));
typedef unsigned short us4 __attribute__((ext_vector_type(4)));
typedef __bf16 bf8v __attribute__((ext_vector_type(8)));
typedef float f4v __attribute__((ext_vector_type(4)));
typedef float fl4 __attribute__((ext_vector_type(4)));

#define LX 516  // x_s row stride (u16): 1032 B = 258 dw == 2 mod 32 -> conflict-free b64 frags
#define LQ 68   // q/k/v/P row stride: 136 B = 34 dw == 2 mod 32
#define LB 36   // out_proj tile stride: 72 B = 18 dw, 18r mod 32 all-distinct for r=0..15

static __device__ __forceinline__ u16 f2bf(float f) {
  union { float f; unsigned u; } v;
  v.f = f;
  unsigned r = v.u + 0x7fffu + ((v.u >> 16) & 1u);  // RNE
  return (u16)(r >> 16);
}

union Frag8 { s4v h[2]; s8v v; };

static __device__ __forceinline__ s8v load_frag(const u16* p) {
  // two 8B LDS reads (addresses only guaranteed 8B-aligned with our strides)
  Frag8 f;
  f.h[0] = *(const s4v*)(p);
  f.h[1] = *(const s4v*)(p + 4);
  return f.v;
}

static __device__ __forceinline__ f4v mfma16(s8v a, s8v b, f4v c) {
  return __builtin_amdgcn_mfma_f32_16x16x32_bf16(
      __builtin_bit_cast(bf8v, a), __builtin_bit_cast(bf8v, b), c, 0, 0, 0);
}

// ---------------------------------------------------------------- weights
__global__ __launch_bounds__(256) void pack_weights_kernel(
    const float* __restrict__ Wq, const float* __restrict__ Wk,
    const float* __restrict__ Wv, const float* __restrict__ Wo,
    u16* __restrict__ Wqkv, u16* __restrict__ Wob) {
  const int i4 = (blockIdx.x * 256 + threadIdx.x) * 4;  // 0..262140
  fl4 a = *(const fl4*)(Wq + i4);
  fl4 b = *(const fl4*)(Wk + i4);
  fl4 c = *(const fl4*)(Wv + i4);
  fl4 d = *(const fl4*)(Wo + i4);
  us4 pa, pb, pc, pd;
#pragma unroll
  for (int t = 0; t < 4; ++t) {
    pa[t] = f2bf(a[t]); pb[t] = f2bf(b[t]);
    pc[t] = f2bf(c[t]); pd[t] = f2bf(d[t]);
  }
  *(us4*)(Wqkv + i4) = pa;
  *(us4*)(Wqkv + 262144 + i4) = pb;
  *(us4*)(Wqkv + 524288 + i4) = pc;
  *(us4*)(Wob + i4) = pd;
}

// ------------------------------------------------- fused QKV + attention
// grid: 2048 (one WG per (b,t)); 512 threads = 8 waves = 2 head-groups x 4
__global__ __launch_bounds__(512) void qkv_attn_kernel(
    const float* __restrict__ x, const u16* __restrict__ Wqkv,
    const float* __restrict__ bq, const float* __restrict__ bk,
    const float* __restrict__ bv, u16* __restrict__ attn) {
  __shared__ u16 x_s[64 * LX];       // 66048 B
  __shared__ u16 qs[2][64 * LQ];     // q' (scaled) per head-group
  __shared__ u16 ks_[2][64 * LQ];
  __shared__ u16 vs[2][64 * LQ];     // stored transposed: vs[d][m]
  __shared__ u16 Ps[2][64 * LQ];     // softmax probs (layout transform)

  const int bt = blockIdx.x;
  const int tid = threadIdx.x;
  const int lane = tid & 63;
  const int wave = tid >> 6;
  const int grp = wave >> 2;  // head-group: 0 -> heads 0..3, 1 -> heads 4..7
  const int w = wave & 3;     // strip id within group
  const int l15 = lane & 15;
  const int l4 = lane >> 4;

  // stage x_bt (64 x 512) fp32 -> bf16 LDS
  {
    const float* xp = x + (size_t)bt * (64 * 512);
    const int c4 = (tid & 127) * 4;
    const int r0 = tid >> 7;
#pragma unroll
    for (int i = 0; i < 16; ++i) {
      const int r = r0 + i * 4;
      fl4 v = *(const fl4*)(xp + r * 512 + c4);
      us4 p;
      p[0] = f2bf(v[0]); p[1] = f2bf(v[1]);
      p[2] = f2bf(v[2]); p[3] = f2bf(v[3]);
      *(us4*)&x_s[r * LX + c4] = p;
    }
  }
  __syncthreads();

  const f4v fzero = {0.f, 0.f, 0.f, 0.f};

  for (int hi = 0; hi < 4; ++hi) {
    const int h = grp * 4 + hi;
    // ---- QKV GEMM: this wave computes cols [16w,16w+16) of q_h/k_h/v_h ----
    const int ncol = h * 64 + 16 * w + l15;  // global output-neuron index
    const float bqv = bq[ncol];
    const float bkv = bk[ncol];
    const float bvv = bv[ncol];
    const u16* WqP = Wqkv + (size_t)ncol * 512 + l4 * 8;
    const u16* WkP = Wqkv + (size_t)(512 + ncol) * 512 + l4 * 8;
    const u16* WvP = Wqkv + (size_t)(1024 + ncol) * 512 + l4 * 8;

    f4v aq[4], ak[4], av[4];
#pragma unroll
    for (int i = 0; i < 4; ++i) { aq[i] = fzero; ak[i] = fzero; av[i] = fzero; }

#pragma unroll
    for (int kk = 0; kk < 16; ++kk) {
      const int ko = kk * 32 + l4 * 8;
      const s8v bq8 = *(const s8v*)(WqP + kk * 32);  // 16B, L2-resident weights
      const s8v bk8 = *(const s8v*)(WkP + kk * 32);
      const s8v bv8 = *(const s8v*)(WvP + kk * 32);
      const s8v a0 = load_frag(&x_s[(0 + l15) * LX + ko]);
      const s8v a1 = load_frag(&x_s[(16 + l15) * LX + ko]);
      const s8v a2 = load_frag(&x_s[(32 + l15) * LX + ko]);
      const s8v a3 = load_frag(&x_s[(48 + l15) * LX + ko]);
      aq[0] = mfma16(a0, bq8, aq[0]); aq[1] = mfma16(a1, bq8, aq[1]);
      aq[2] = mfma16(a2, bq8, aq[2]); aq[3] = mfma16(a3, bq8, aq[3]);
      ak[0] = mfma16(a0, bk8, ak[0]); ak[1] = mfma16(a1, bk8, ak[1]);
      ak[2] = mfma16(a2, bk8, ak[2]); ak[3] = mfma16(a3, bk8, ak[3]);
      av[0] = mfma16(a0, bv8, av[0]); av[1] = mfma16(a1, bv8, av[1]);
      av[2] = mfma16(a2, bv8, av[2]); av[3] = mfma16(a3, bv8, av[3]);
    }

    // epilogue: bias (+ 1/sqrt(DK) folded into q), write bf16 to LDS
    const int nl = 16 * w + l15;
#pragma unroll
    for (int i = 0; i < 4; ++i) {
#pragma unroll
      for (int r = 0; r < 4; ++r) {
        const int m = 16 * i + 4 * l4 + r;  // C-layout row
        qs[grp][m * LQ + nl] = f2bf((aq[i][r] + bqv) * 0.125f);
        ks_[grp][m * LQ + nl] = f2bf(ak[i][r] + bkv);
        vs[grp][nl * LQ + m] = f2bf(av[i][r] + bvv);  // transposed for PV B-frags
      }
    }
    __syncthreads();

    // ---- S = q' k^T : wave owns rows [16w,16w+16), all 64 cols ----
    f4v s[4];
#pragma unroll
    for (int j = 0; j < 4; ++j) s[j] = fzero;
#pragma unroll
    for (int kc = 0; kc < 2; ++kc) {
      const s8v af = load_frag(&qs[grp][(16 * w + l15) * LQ + kc * 32 + l4 * 8]);
#pragma unroll
      for (int j = 0; j < 4; ++j) {
        const s8v bf = load_frag(&ks_[grp][(16 * j + l15) * LQ + kc * 32 + l4 * 8]);
        s[j] = mfma16(af, bf, s[j]);
      }
    }
    // softmax over 64 cols: 4 regs (col-tiles) x 16 lanes of the quad-group
#pragma unroll
    for (int r = 0; r < 4; ++r) {
      float mx = fmaxf(fmaxf(s[0][r], s[1][r]), fmaxf(s[2][r], s[3][r]));
      mx = fmaxf(mx, __shfl_xor(mx, 1));
      mx = fmaxf(mx, __shfl_xor(mx, 2));
      mx = fmaxf(mx, __shfl_xor(mx, 4));
      mx = fmaxf(mx, __shfl_xor(mx, 8));
      float e0 = __expf(s[0][r] - mx);
      float e1 = __expf(s[1][r] - mx);
      float e2 = __expf(s[2][r] - mx);
      float e3 = __expf(s[3][r] - mx);
      float sm = e0 + e1 + e2 + e3;
      sm += __shfl_xor(sm, 1);
      sm += __shfl_xor(sm, 2);
      sm += __shfl_xor(sm, 4);
      sm += __shfl_xor(sm, 8);
      const float inv = __builtin_amdgcn_rcpf(sm);
      s[0][r] = e0 * inv; s[1][r] = e1 * inv;
      s[2][r] = e2 * inv; s[3][r] = e3 * inv;
    }
    // P: C-layout -> LDS (A-layout consumed below)
#pragma unroll
    for (int j = 0; j < 4; ++j)
#pragma unroll
      for (int r = 0; r < 4; ++r)
        Ps[grp][(16 * w + 4 * l4 + r) * LQ + 16 * j + l15] = f2bf(s[j][r]);
    __syncthreads();

    // ---- O = P @ V : rows [16w,16w+16) ----
    f4v o[4];
#pragma unroll
    for (int j = 0; j < 4; ++j) o[j] = fzero;
#pragma unroll
    for (int kc = 0; kc < 2; ++kc) {
      const s8v af = load_frag(&Ps[grp][(16 * w + l15) * LQ + kc * 32 + l4 * 8]);
#pragma unroll
      for (int j = 0; j < 4; ++j) {
        const s8v bf = load_frag(&vs[grp][(16 * j + l15) * LQ + kc * 32 + l4 * 8]);
        o[j] = mfma16(af, bf, o[j]);
      }
    }
    u16* ap = attn + (size_t)(bt * 64) * 512 + h * 64;
#pragma unroll
    for (int j = 0; j < 4; ++j)
#pragma unroll
      for (int r = 0; r < 4; ++r)
        ap[(size_t)(16 * w + 4 * l4 + r) * 512 + 16 * j + l15] = f2bf(o[j][r]);
    __syncthreads();  // protect qs/ks/vs/Ps before next head
  }
}

// ------------------------------------------------- output projection GEMM
// out[131072][512] = attn(bf16) @ Wo^T + bo ; 128x128 tiles, BK=32
__global__ __launch_bounds__(256) void out_proj_kernel(
    const u16* __restrict__ attn, const u16* __restrict__ Wob,
    const float* __restrict__ bo, float* __restrict__ out) {
  __shared__ u16 As[128 * LB];
  __shared__ u16 Bs[128 * LB];
  const int m0 = blockIdx.x * 128;
  const int n0 = blockIdx.y * 128;
  const int tid = threadIdx.x;
  const int lane = tid & 63;
  const int wave = tid >> 6;
  const int wy = wave >> 1;
  const int wx = wave & 1;
  const int l15 = lane & 15;
  const int l4 = lane >> 4;

  const f4v fzero = {0.f, 0.f, 0.f, 0.f};
  f4v acc[4][4];
#pragma unroll
  for (int i = 0; i < 4; ++i)
#pragma unroll
    for (int j = 0; j < 4; ++j) acc[i][j] = fzero;

  const int row0 = tid >> 2, cc0 = (tid & 3) * 8;
  const int c1 = tid + 256;
  const int row1 = c1 >> 2, cc1 = (c1 & 3) * 8;

  for (int k0 = 0; k0 < 512; k0 += 32) {
    __syncthreads();
    {
      Frag8 ga0, gb0, ga1, gb1;
      ga0.v = *(const s8v*)(attn + (size_t)(m0 + row0) * 512 + k0 + cc0);
      gb0.v = *(const s8v*)(Wob + (size_t)(n0 + row0) * 512 + k0 + cc0);
      ga1.v = *(const s8v*)(attn + (size_t)(m0 + row1) * 512 + k0 + cc1);
      gb1.v = *(const s8v*)(Wob + (size_t)(n0 + row1) * 512 + k0 + cc1);
      *(s4v*)&As[row0 * LB + cc0] = ga0.h[0];
      *(s4v*)&As[row0 * LB + cc0 + 4] = ga0.h[1];
      *(s4v*)&Bs[row0 * LB + cc0] = gb0.h[0];
      *(s4v*)&Bs[row0 * LB + cc0 + 4] = gb0.h[1];
      *(s4v*)&As[row1 * LB + cc1] = ga1.h[0];
      *(s4v*)&As[row1 * LB + cc1 + 4] = ga1.h[1];
      *(s4v*)&Bs[row1 * LB + cc1] = gb1.h[0];
      *(s4v*)&Bs[row1 * LB + cc1 + 4] = gb1.h[1];
    }
    __syncthreads();
    s8v a[4], b[4];
#pragma unroll
    for (int i = 0; i < 4; ++i)
      a[i] = load_frag(&As[(wy * 64 + 16 * i + l15) * LB + l4 * 8]);
#pragma unroll
    for (int j = 0; j < 4; ++j)
      b[j] = load_frag(&Bs[(wx * 64 + 16 * j + l15) * LB + l4 * 8]);
#pragma unroll
    for (int i = 0; i < 4; ++i)
#pragma unroll
      for (int j = 0; j < 4; ++j)
        acc[i][j] = mfma16(a[i], b[j], acc[i][j]);
  }
#pragma unroll
  for (int j = 0; j < 4; ++j) {
    const int col = n0 + wx * 64 + 16 * j + l15;
    const float bb = bo[col];
#pragma unroll
    for (int i = 0; i < 4; ++i) {
#pragma unroll
      for (int r = 0; r < 4; ++r) {
        const int row = m0 + wy * 64 + 16 * i + 4 * l4 + r;
        out[(size_t)row * 512 + col] = acc[i][j][r] + bb;
      }
    }
  }
}

extern "C" void kernel_launch(void* const* d_in, const int* in_sizes, int n_in,
                              void* d_out, int out_size, void* d_ws, size_t ws_size,
                              hipStream_t stream) {
  const float* x  = (const float*)d_in[0];
  const float* Wq = (const float*)d_in[1];
  const float* bq = (const float*)d_in[2];
  const float* Wk = (const float*)d_in[3];
  const float* bk = (const float*)d_in[4];
  const float* Wv = (const float*)d_in[5];
  const float* bv = (const float*)d_in[6];
  const float* Wo = (const float*)d_in[7];
  const float* bo = (const float*)d_in[8];
  float* out = (float*)d_out;

  // workspace layout (needs 136,314,880 B):
  u16* Wqkv = (u16*)d_ws;              // [1536][512] bf16 = 1,572,864 B
  u16* Wob  = Wqkv + 3 * 512 * 512;    // [512][512]  bf16 =   524,288 B
  u16* attn = Wob + 512 * 512;         // [131072][512] bf16 = 134,217,728 B

  pack_weights_kernel<<<256, 256, 0, stream>>>(Wq, Wk, Wv, Wo, Wqkv, Wob);
  qkv_attn_kernel<<<2048, 512, 0, stream>>>(x, Wqkv, bq, bk, bv, attn);
  out_proj_kernel<<<dim3(1024, 4), 256, 0, stream>>>(attn, Wob, bo, out);
}